// Round 7
// baseline (239.829 us; speedup 1.0000x reference)
//
#include <hip/hip_runtime.h>

#define PGRID 576
#define NB0   64
#define CIN   256
#define KNN   9
#define NNODE (NB0 * PGRID)   // 36864

typedef __attribute__((ext_vector_type(8))) short short8;
typedef __attribute__((ext_vector_type(4))) float f32x4;

__device__ __forceinline__ float bf2f(unsigned short u) {
    union { unsigned int i; float f; } v; v.i = ((unsigned int)u) << 16; return v.f;
}
__device__ __forceinline__ unsigned short f2b(float f) {
    unsigned int u = __float_as_uint(f);
    return (unsigned short)((u + 0x7FFFu + ((u >> 16) & 1u)) >> 16);
}

// ---------------------------------------------------------------------------
// P1: Wt[j][c] = bf16(W[c][j])
// ---------------------------------------------------------------------------
__global__ __launch_bounds__(256) void prep_w(const float* __restrict__ W,
                                              unsigned short* __restrict__ Wt) {
    __shared__ float tile[64][65];
    const int c0 = blockIdx.x * 64, j0 = blockIdx.y * 64;
    const int t = threadIdx.x, lo = t % 64, hi = t / 64;
#pragma unroll
    for (int r = 0; r < 16; ++r)
        tile[r * 4 + hi][lo] = W[(size_t)(c0 + r * 4 + hi) * 256 + j0 + lo];
    __syncthreads();
#pragma unroll
    for (int r = 0; r < 16; ++r)
        Wt[(size_t)(j0 + r * 4 + hi) * 256 + c0 + lo] = f2b(tile[lo][r * 4 + hi]);
}

// ---------------------------------------------------------------------------
// K1: fused GEMM + att-score epilogue. NO LDS, NO barriers.
// mfma(W_frag, x_frag): D col = p (lane&15), row = j (f*16 + l4*4 + r).
// W-frags read directly from L2-resident Wt (16B/lane, 1KB/instr).
// x read once from HBM (scalar, 64B-segment coalesced).
// ---------------------------------------------------------------------------
__global__ __launch_bounds__(256) void gemm_fused(
    const float* __restrict__ x, const unsigned short* __restrict__ Wt,
    const float* __restrict__ att_src, const float* __restrict__ att_dst,
    unsigned short* __restrict__ h, float* __restrict__ as_, float* __restrict__ ad_) {
    const int bx = blockIdx.x;
    const int t  = threadIdx.x;
    const int b  = bx / 9;
    const int p0 = (bx % 9) * 64;
    const int n0 = bx * 64;
    const int l = t & 63, w = t >> 6;
    const int l4 = l >> 4, l15 = l & 15;
    const float* xb = x + (size_t)b * (CIN * PGRID);
    const int prow = p0 + w * 16 + l15;

    // ---- x loads: 64 scalar f32 (issued first; HBM latency under the rest)
    float a0[64];
#pragma unroll
    for (int cq = 0; cq < 8; ++cq)
#pragma unroll
        for (int jj = 0; jj < 8; ++jj) {
            int c = cq * 32 + l4 * 8 + jj;
            a0[cq * 8 + jj] = xb[(size_t)c * PGRID + prow];
        }
    short8 apk[8];
#pragma unroll
    for (int cq = 0; cq < 8; ++cq) {
        short8 v;
#pragma unroll
        for (int jj = 0; jj < 8; ++jj) v[jj] = (short)f2b(a0[cq * 8 + jj]);
        apk[cq] = v;
    }

    // ---- K-loop: W-frag straight from global (L2), no LDS
    f32x4 acc[16] = {};
    const unsigned short* wbase = Wt + (size_t)l15 * 256 + l4 * 8;
#pragma unroll
    for (int q = 0; q < 8; ++q) {
#pragma unroll
        for (int f = 0; f < 16; ++f) {
            short8 wf = *(const short8*)(wbase + (size_t)f * 4096 + q * 32);
            acc[f] = __builtin_amdgcn_mfma_f32_16x16x32_bf16(wf, apk[q], acc[f], 0, 0, 0);
        }
    }

    // ---- epilogue: h row write (lane owns p = prow; j = f*16 + l4*4 + r)
    unsigned short* hrow = h + (size_t)(n0 + w * 16 + l15) * 256 + l4 * 4;
#pragma unroll
    for (int f = 0; f < 16; ++f) {
        uint2 pk;
        pk.x = (unsigned int)f2b(acc[f][0]) | ((unsigned int)f2b(acc[f][1]) << 16);
        pk.y = (unsigned int)f2b(acc[f][2]) | ((unsigned int)f2b(acc[f][3]) << 16);
        *(uint2*)(hrow + f * 16) = pk;
    }

    // ---- epilogue: att scores, in-lane dot + 2 shuffles (reduce over l4)
    float s0 = 0.f, s1 = 0.f, d0 = 0.f, d1 = 0.f;
#pragma unroll
    for (int f = 0; f < 16; ++f) {
        float4 av = *(const float4*)(att_src + f * 16 + l4 * 4);
        float4 dv = *(const float4*)(att_dst + f * 16 + l4 * 4);
        float ss = acc[f][0] * av.x + acc[f][1] * av.y + acc[f][2] * av.z + acc[f][3] * av.w;
        float dd = acc[f][0] * dv.x + acc[f][1] * dv.y + acc[f][2] * dv.z + acc[f][3] * dv.w;
        if (f < 8) { s0 += ss; d0 += dd; } else { s1 += ss; d1 += dd; }
    }
    s0 += __shfl_xor(s0, 16); s0 += __shfl_xor(s0, 32);
    s1 += __shfl_xor(s1, 16); s1 += __shfl_xor(s1, 32);
    d0 += __shfl_xor(d0, 16); d0 += __shfl_xor(d0, 32);
    d1 += __shfl_xor(d1, 16); d1 += __shfl_xor(d1, 32);
    if (l < 16) {
        int n = n0 + w * 16 + l;
        float2 sv; sv.x = s0; sv.y = s1;
        float2 dv2; dv2.x = d0; dv2.y = d1;
        *(float2*)(as_ + 2 * n) = sv;
        *(float2*)(ad_ + 2 * n) = dv2;
    }
}

// ---------------------------------------------------------------------------
// K3: space GAT gather — 4 nodes/block, 64 lanes/node, uint2 (8B)/lane:
// each h-row read is one fully-coalesced 512B wave instruction.
// ---------------------------------------------------------------------------
__global__ __launch_bounds__(256) void space_gather(
    const unsigned short* __restrict__ h, const float* __restrict__ as_,
    const float* __restrict__ ad_, const int* __restrict__ esrc,
    const float* __restrict__ bias, unsigned short* __restrict__ xsb) {
    const int t = threadIdx.x;
    const int g = t >> 6, l = t & 63;
    const int n = blockIdx.x * 4 + g;
    int srcs[10];
#pragma unroll
    for (int k = 0; k < 9; ++k) srcs[k] = esrc[n * 9 + k];
    srcs[9] = n;
    const int head = l >> 5;              // j4 >= 128 <=> l >= 32
    const float adv = ad_[n * 2 + head];
    float e[10];
    float m = -1e30f;
#pragma unroll
    for (int k = 0; k < 10; ++k) {
        float ev = as_[srcs[k] * 2 + head] + adv;
        ev = ev >= 0.f ? ev : 0.2f * ev;
        e[k] = ev; m = fmaxf(m, ev);
    }
    float ssum = 0.f;
#pragma unroll
    for (int k = 0; k < 10; ++k) { e[k] = __expf(e[k] - m); ssum += e[k]; }
    const float inv = 1.f / (ssum + 1e-16f);
    const int j4 = l * 4;
    float o0 = 0.f, o1 = 0.f, o2 = 0.f, o3 = 0.f;
#pragma unroll
    for (int k = 0; k < 10; ++k) {
        uint2 v = *(const uint2*)(h + (size_t)srcs[k] * 256 + j4);
        o0 += e[k] * bf2f((unsigned short)(v.x & 0xffff));
        o1 += e[k] * bf2f((unsigned short)(v.x >> 16));
        o2 += e[k] * bf2f((unsigned short)(v.y & 0xffff));
        o3 += e[k] * bf2f((unsigned short)(v.y >> 16));
    }
    float4 bi = *(const float4*)(bias + j4);
    o0 = o0 * inv + bi.x; o1 = o1 * inv + bi.y;
    o2 = o2 * inv + bi.z; o3 = o3 * inv + bi.w;
    uint2 pk;
    pk.x = (unsigned int)f2b(o0) | ((unsigned int)f2b(o1) << 16);
    pk.y = (unsigned int)f2b(o2) | ((unsigned int)f2b(o3) << 16);
    *(uint2*)(xsb + (size_t)n * 256 + j4) = pk;
}

// ---------------------------------------------------------------------------
// K4: pool partials — grid(64,9), 4 p-subtiles of 16 rows, uint2 loads
// ---------------------------------------------------------------------------
__global__ __launch_bounds__(256) void pool_partial(const unsigned short* __restrict__ xsb,
                                                    float* __restrict__ embp) {
    __shared__ float red[4][256];
    const int b = blockIdx.x, seg = blockIdx.y;
    const int t = threadIdx.x;
    const int l = t & 63, sub = t >> 6;
    const int j4 = l * 4;
    const unsigned short* base = xsb + ((size_t)b * PGRID + seg * 64 + sub * 16) * 256 + j4;
    float s0 = 0.f, s1 = 0.f, s2 = 0.f, s3 = 0.f;
#pragma unroll
    for (int p = 0; p < 16; ++p) {
        uint2 v = *(const uint2*)(base + (size_t)p * 256);
        s0 += bf2f((unsigned short)(v.x & 0xffff));
        s1 += bf2f((unsigned short)(v.x >> 16));
        s2 += bf2f((unsigned short)(v.y & 0xffff));
        s3 += bf2f((unsigned short)(v.y >> 16));
    }
    float4 sv; sv.x = s0; sv.y = s1; sv.z = s2; sv.w = s3;
    *(float4*)(&red[sub][j4]) = sv;
    __syncthreads();
    if (sub == 0) {
        float4 a = *(float4*)(&red[1][j4]);
        float4 c = *(float4*)(&red[2][j4]);
        float4 d = *(float4*)(&red[3][j4]);
        float4 r;
        r.x = s0 + a.x + c.x + d.x;
        r.y = s1 + a.y + c.y + d.y;
        r.z = s2 + a.z + c.z + d.z;
        r.w = s3 + a.w + c.w + d.w;
        *(float4*)(embp + ((size_t)b * 9 + seg) * 256 + j4) = r;
    }
}

// ---------------------------------------------------------------------------
// K5: view linear + scalar scores (embp holds 9 partial SUMS per image)
// ---------------------------------------------------------------------------
__global__ __launch_bounds__(256) void view_linear(const float* __restrict__ embp,
                                                   const float* __restrict__ Wv,
                                                   const float* __restrict__ att_s,
                                                   const float* __restrict__ att_d,
                                                   float* __restrict__ hv,
                                                   float* __restrict__ asv,
                                                   float* __restrict__ adv) {
    __shared__ float er[256];
    __shared__ float red[2][256];
    const int i = blockIdx.x;
    const int j = threadIdx.x;
    const int i64 = i & 63;
    float s = 0.f;
#pragma unroll
    for (int seg = 0; seg < 9; ++seg) s += embp[((size_t)i64 * 9 + seg) * 256 + j];
    er[j] = s * (1.f / 576.f);
    __syncthreads();
    float acc = 0.f;
    for (int c = 0; c < 256; ++c) acc += er[c] * Wv[c * 256 + j];
    hv[(size_t)i * 256 + j] = acc;
    red[0][j] = acc * att_s[j];
    red[1][j] = acc * att_d[j];
    __syncthreads();
    for (int off = 128; off > 0; off >>= 1) {
        if (j < off) { red[0][j] += red[0][j + off]; red[1][j] += red[1][j + off]; }
        __syncthreads();
    }
    if (j == 0) { asv[i] = red[0][0]; adv[i] = red[1][0]; }
}

// ---------------------------------------------------------------------------
// K6: view GAT gather for dst 0..63
// ---------------------------------------------------------------------------
__global__ __launch_bounds__(256) void view_gather(const float* __restrict__ hv,
                                                   const float* __restrict__ asv,
                                                   const float* __restrict__ adv,
                                                   const int* __restrict__ ev,
                                                   int Ev,
                                                   const float* __restrict__ bias,
                                                   float* __restrict__ feat) {
    __shared__ int cnt;
    __shared__ int s_src[32];
    const int d = blockIdx.x;
    const int t = threadIdx.x;
    if (t == 0) cnt = 0;
    __syncthreads();
    for (int e = t; e < Ev; e += 256) {
        if (ev[Ev + e] == d) {
            int pos = atomicAdd(&cnt, 1);
            s_src[pos] = ev[e];
        }
    }
    __syncthreads();
    const int ns = cnt;
    const float adval = adv[d];
    float m = -1e30f;
    float ev_[16];
#pragma unroll 1
    for (int k = 0; k < ns; ++k) {
        float e = asv[s_src[k]] + adval;
        e = e >= 0.f ? e : 0.2f * e;
        ev_[k] = e;
        m = fmaxf(m, e);
    }
    float eself = asv[d] + adval;
    eself = eself >= 0.f ? eself : 0.2f * eself;
    m = fmaxf(m, eself);
    float ssum = 0.f;
#pragma unroll 1
    for (int k = 0; k < ns; ++k) { ev_[k] = __expf(ev_[k] - m); ssum += ev_[k]; }
    float wself = __expf(eself - m);
    ssum += wself;
    const float inv = 1.f / (ssum + 1e-16f);
    float out = 0.f;
#pragma unroll 1
    for (int k = 0; k < ns; ++k) out += ev_[k] * hv[(size_t)s_src[k] * 256 + t];
    out += wself * hv[(size_t)d * 256 + t];
    feat[d * 256 + t] = out * inv + bias[t];
}

// ---------------------------------------------------------------------------
// K7: out = 0.5*xs(bf16) + 0.5*feat[b]
// ---------------------------------------------------------------------------
__global__ __launch_bounds__(256) void combine(const unsigned short* __restrict__ xsb,
                                               const float* __restrict__ feat,
                                               float* __restrict__ out, int ntot4) {
    int i = blockIdx.x * blockDim.x + threadIdx.x;
    if (i >= ntot4) return;
    size_t f = (size_t)i * 4;
    int b = (int)(f / (PGRID * 256));
    int j = (int)(f & 255);
    uint2 v = *(const uint2*)(xsb + f);
    float4 fb = *(const float4*)(feat + b * 256 + j);
    float4 o;
    o.x = 0.5f * (bf2f((unsigned short)(v.x & 0xffff)) + fb.x);
    o.y = 0.5f * (bf2f((unsigned short)(v.x >> 16))   + fb.y);
    o.z = 0.5f * (bf2f((unsigned short)(v.y & 0xffff)) + fb.z);
    o.w = 0.5f * (bf2f((unsigned short)(v.y >> 16))   + fb.w);
    *(float4*)(out + f) = o;
}

// ---------------------------------------------------------------------------
extern "C" void kernel_launch(void* const* d_in, const int* in_sizes, int n_in,
                              void* d_out, int out_size, void* d_ws, size_t ws_size,
                              hipStream_t stream) {
    const float* x        = (const float*)d_in[0];
    const int*   e_space  = (const int*)d_in[3];
    const int*   e_view   = (const int*)d_in[4];
    const float* W_space  = (const float*)d_in[5];
    const float* att_ss   = (const float*)d_in[6];
    const float* att_ds   = (const float*)d_in[7];
    const float* bias_s   = (const float*)d_in[8];
    const float* W_view   = (const float*)d_in[9];
    const float* att_sv   = (const float*)d_in[10];
    const float* att_dv   = (const float*)d_in[11];
    const float* bias_v   = (const float*)d_in[12];
    float* out = (float*)d_out;

    const int Ev = in_sizes[4] / 2;

    // workspace layout (bytes)
    char* ws = (char*)d_ws;
    unsigned short* hbf = (unsigned short*)ws;                       // 18.9 MB
    unsigned short* Wt  = (unsigned short*)(ws + 18874368);          // 128 KB
    unsigned short* xsb = (unsigned short*)(ws + 18874368 + 131072); // 18.9 MB
    float* as_  = (float*)(ws + 2 * 18874368 + 131072);
    float* ad_  = as_ + NNODE * 2;
    float* embp = ad_ + NNODE * 2;                                   // 64*9*256
    float* hv   = embp + 64 * 9 * 256;
    float* asv  = hv  + 128 * 256;
    float* adv  = asv + 128;
    float* feat = adv + 128;

    prep_w<<<dim3(4, 4), 256, 0, stream>>>(W_space, Wt);
    gemm_fused<<<576, 256, 0, stream>>>(x, Wt, att_ss, att_ds, hbf, as_, ad_);
    space_gather<<<NNODE / 4, 256, 0, stream>>>(hbf, as_, ad_, e_space, bias_s, xsb);
    pool_partial<<<dim3(NB0, 9), 256, 0, stream>>>(xsb, embp);
    view_linear<<<128, 256, 0, stream>>>(embp, W_view, att_sv, att_dv, hv, asv, adv);
    view_gather<<<NB0, 256, 0, stream>>>(hv, asv, adv, e_view, Ev, bias_v, feat);

    const int ntot4 = NB0 * PGRID * 256 / 4;
    combine<<<(ntot4 + 255) / 256, 256, 0, stream>>>(xsb, feat, out, ntot4);
}

// Round 8
// 208.667 us; speedup vs baseline: 1.1493x; 1.1493x over previous
//
#include <hip/hip_runtime.h>

#define PGRID 576
#define NB0   64
#define CIN   256
#define KNN   9
#define NNODE (NB0 * PGRID)   // 36864

typedef __attribute__((ext_vector_type(8))) short short8;
typedef __attribute__((ext_vector_type(4))) float f32x4;

__device__ __forceinline__ float bf2f(unsigned short u) {
    union { unsigned int i; float f; } v; v.i = ((unsigned int)u) << 16; return v.f;
}
__device__ __forceinline__ unsigned short f2b(float f) {
    unsigned int u = __float_as_uint(f);
    return (unsigned short)((u + 0x7FFFu + ((u >> 16) & 1u)) >> 16);
}

// ---------------------------------------------------------------------------
// P1: Wt[j][c] = bf16(W[c][j])
// ---------------------------------------------------------------------------
__global__ __launch_bounds__(256) void prep_w(const float* __restrict__ W,
                                              unsigned short* __restrict__ Wt) {
    __shared__ float tile[64][65];
    const int c0 = blockIdx.x * 64, j0 = blockIdx.y * 64;
    const int t = threadIdx.x, lo = t % 64, hi = t / 64;
#pragma unroll
    for (int r = 0; r < 16; ++r)
        tile[r * 4 + hi][lo] = W[(size_t)(c0 + r * 4 + hi) * 256 + j0 + lo];
    __syncthreads();
#pragma unroll
    for (int r = 0; r < 16; ++r)
        Wt[(size_t)(j0 + r * 4 + hi) * 256 + c0 + lo] = f2b(tile[lo][r * 4 + hi]);
}

// ---------------------------------------------------------------------------
// K1: fused GEMM + att-score epilogue.
// mfma(W_frag, x_frag): lane owns h-row p; W from double-buffered LDS.
// 4 chunks of BK=64c; per iter: STAGE(next buf) -> MFMA(cur buf) -> barrier
// (barrier's vmcnt(0) drain IS the T3 counted-wait; staging hides under MFMA).
// LDS layout per chunk: [j=256][granule 8 of 16B], granule ^= (j&7) swizzle,
// staged via pre-swizzled global source (linear LDS dest).
// ---------------------------------------------------------------------------
__global__ __launch_bounds__(256) void gemm_fused(
    const float* __restrict__ x, const unsigned short* __restrict__ Wt,
    const float* __restrict__ att_src, const float* __restrict__ att_dst,
    unsigned short* __restrict__ h, float* __restrict__ as_, float* __restrict__ ad_) {
    __shared__ char ldsB[2][32768];
    const int bx = blockIdx.x;
    const int t  = threadIdx.x;
    const int b  = bx / 9;
    const int p0 = (bx % 9) * 64;
    const int n0 = bx * 64;
    const int l = t & 63, w = t >> 6;
    const int l4 = l >> 4, l15 = l & 15;
    const float* xb = x + (size_t)b * (CIN * PGRID);
    const int prow = p0 + w * 16 + l15;

#define STAGE_CHUNK(bufsel, ck)                                               \
    {                                                                         \
        _Pragma("unroll")                                                     \
        for (int pass = 0; pass < 8; ++pass) {                                \
            const int byte_ = pass * 4096 + t * 16;                           \
            const int j_    = byte_ >> 7;                                     \
            const int g_    = (byte_ >> 4) & 7;                               \
            const int gs_   = g_ ^ (j_ & 7);                                  \
            __builtin_amdgcn_global_load_lds(                                 \
                (const char*)Wt + (size_t)j_ * 512 + (ck) * 128 + gs_ * 16,   \
                &ldsB[bufsel][pass * 4096 + (t & 192) * 16], 16, 0, 0);       \
        }                                                                     \
    }

    // ---- x loads: 64 scalar f32, issued first (HBM latency under the rest)
    float a0[64];
#pragma unroll
    for (int cq = 0; cq < 8; ++cq)
#pragma unroll
        for (int jj = 0; jj < 8; ++jj) {
            int c = cq * 32 + l4 * 8 + jj;
            a0[cq * 8 + jj] = xb[(size_t)c * PGRID + prow];
        }

    // ---- prologue: stage chunk 0
    STAGE_CHUNK(0, 0);

    short8 apk[8];
#pragma unroll
    for (int cq = 0; cq < 8; ++cq) {
        short8 v;
#pragma unroll
        for (int jj = 0; jj < 8; ++jj) v[jj] = (short)f2b(a0[cq * 8 + jj]);
        apk[cq] = v;
    }

    f32x4 acc[16] = {};
    __syncthreads();                    // chunk 0 staged (vmcnt drained)

#pragma unroll
    for (int ck = 0; ck < 4; ++ck) {
        if (ck < 3) STAGE_CHUNK((ck + 1) & 1, ck + 1);
        const int cur = ck & 1;
#pragma unroll
        for (int q = 0; q < 2; ++q) {
            const int qq = ck * 2 + q;
#pragma unroll
            for (int f = 0; f < 16; ++f) {
                const int j  = f * 16 + l15;
                const int gs = (q * 4 + l4) ^ (l15 & 7);
                short8 wf = *(const short8*)&ldsB[cur][j * 128 + gs * 16];
                acc[f] = __builtin_amdgcn_mfma_f32_16x16x32_bf16(wf, apk[qq], acc[f], 0, 0, 0);
            }
        }
        if (ck < 3) __syncthreads();    // drains this iter's stage; next buf ready
    }
#undef STAGE_CHUNK

    // ---- epilogue: h row write (lane owns p = prow; j = f*16 + l4*4 + r)
    unsigned short* hrow = h + (size_t)(n0 + w * 16 + l15) * 256 + l4 * 4;
#pragma unroll
    for (int f = 0; f < 16; ++f) {
        uint2 pk;
        pk.x = (unsigned int)f2b(acc[f][0]) | ((unsigned int)f2b(acc[f][1]) << 16);
        pk.y = (unsigned int)f2b(acc[f][2]) | ((unsigned int)f2b(acc[f][3]) << 16);
        *(uint2*)(hrow + f * 16) = pk;
    }

    // ---- epilogue: att scores, in-lane dot + 2 shuffles (reduce over l4)
    float s0 = 0.f, s1 = 0.f, d0 = 0.f, d1 = 0.f;
#pragma unroll
    for (int f = 0; f < 16; ++f) {
        float4 av = *(const float4*)(att_src + f * 16 + l4 * 4);
        float4 dv = *(const float4*)(att_dst + f * 16 + l4 * 4);
        float ss = acc[f][0] * av.x + acc[f][1] * av.y + acc[f][2] * av.z + acc[f][3] * av.w;
        float dd = acc[f][0] * dv.x + acc[f][1] * dv.y + acc[f][2] * dv.z + acc[f][3] * dv.w;
        if (f < 8) { s0 += ss; d0 += dd; } else { s1 += ss; d1 += dd; }
    }
    s0 += __shfl_xor(s0, 16); s0 += __shfl_xor(s0, 32);
    s1 += __shfl_xor(s1, 16); s1 += __shfl_xor(s1, 32);
    d0 += __shfl_xor(d0, 16); d0 += __shfl_xor(d0, 32);
    d1 += __shfl_xor(d1, 16); d1 += __shfl_xor(d1, 32);
    if (l < 16) {
        int n = n0 + w * 16 + l;
        float2 sv; sv.x = s0; sv.y = s1;
        float2 dv2; dv2.x = d0; dv2.y = d1;
        *(float2*)(as_ + 2 * n) = sv;
        *(float2*)(ad_ + 2 * n) = dv2;
    }
}

// ---------------------------------------------------------------------------
// K3: space GAT gather — 4 nodes/block, 64 lanes/node, uint2 (8B)/lane.
// XCD-bijective swizzle: contiguous 1152-block chunk per XCD so repeated
// neighbor h-rows (spatial knn) are L2-local (band = 2.3MB <= 4MB L2/XCD).
// ---------------------------------------------------------------------------
__global__ __launch_bounds__(256) void space_gather(
    const unsigned short* __restrict__ h, const float* __restrict__ as_,
    const float* __restrict__ ad_, const int* __restrict__ esrc,
    const float* __restrict__ bias, unsigned short* __restrict__ xsb) {
    const int orig = blockIdx.x;                       // 9216 blocks, %8==0
    const int blk  = (orig & 7) * (NNODE / 4 / 8) + (orig >> 3);
    const int t = threadIdx.x;
    const int g = t >> 6, l = t & 63;
    const int n = blk * 4 + g;
    int srcs[10];
#pragma unroll
    for (int k = 0; k < 9; ++k) srcs[k] = esrc[n * 9 + k];
    srcs[9] = n;
    const int head = l >> 5;              // j4 >= 128 <=> l >= 32
    const float adv = ad_[n * 2 + head];
    float e[10];
    float m = -1e30f;
#pragma unroll
    for (int k = 0; k < 10; ++k) {
        float ev = as_[srcs[k] * 2 + head] + adv;
        ev = ev >= 0.f ? ev : 0.2f * ev;
        e[k] = ev; m = fmaxf(m, ev);
    }
    float ssum = 0.f;
#pragma unroll
    for (int k = 0; k < 10; ++k) { e[k] = __expf(e[k] - m); ssum += e[k]; }
    const float inv = 1.f / (ssum + 1e-16f);
    const int j4 = l * 4;
    float o0 = 0.f, o1 = 0.f, o2 = 0.f, o3 = 0.f;
#pragma unroll
    for (int k = 0; k < 10; ++k) {
        uint2 v = *(const uint2*)(h + (size_t)srcs[k] * 256 + j4);
        o0 += e[k] * bf2f((unsigned short)(v.x & 0xffff));
        o1 += e[k] * bf2f((unsigned short)(v.x >> 16));
        o2 += e[k] * bf2f((unsigned short)(v.y & 0xffff));
        o3 += e[k] * bf2f((unsigned short)(v.y >> 16));
    }
    float4 bi = *(const float4*)(bias + j4);
    o0 = o0 * inv + bi.x; o1 = o1 * inv + bi.y;
    o2 = o2 * inv + bi.z; o3 = o3 * inv + bi.w;
    uint2 pk;
    pk.x = (unsigned int)f2b(o0) | ((unsigned int)f2b(o1) << 16);
    pk.y = (unsigned int)f2b(o2) | ((unsigned int)f2b(o3) << 16);
    *(uint2*)(xsb + (size_t)n * 256 + j4) = pk;
}

// ---------------------------------------------------------------------------
// K4: pool partials — grid(64,9), 4 p-subtiles of 16 rows, uint2 loads
// ---------------------------------------------------------------------------
__global__ __launch_bounds__(256) void pool_partial(const unsigned short* __restrict__ xsb,
                                                    float* __restrict__ embp) {
    __shared__ float red[4][256];
    const int b = blockIdx.x, seg = blockIdx.y;
    const int t = threadIdx.x;
    const int l = t & 63, sub = t >> 6;
    const int j4 = l * 4;
    const unsigned short* base = xsb + ((size_t)b * PGRID + seg * 64 + sub * 16) * 256 + j4;
    float s0 = 0.f, s1 = 0.f, s2 = 0.f, s3 = 0.f;
#pragma unroll
    for (int p = 0; p < 16; ++p) {
        uint2 v = *(const uint2*)(base + (size_t)p * 256);
        s0 += bf2f((unsigned short)(v.x & 0xffff));
        s1 += bf2f((unsigned short)(v.x >> 16));
        s2 += bf2f((unsigned short)(v.y & 0xffff));
        s3 += bf2f((unsigned short)(v.y >> 16));
    }
    float4 sv; sv.x = s0; sv.y = s1; sv.z = s2; sv.w = s3;
    *(float4*)(&red[sub][j4]) = sv;
    __syncthreads();
    if (sub == 0) {
        float4 a = *(float4*)(&red[1][j4]);
        float4 c = *(float4*)(&red[2][j4]);
        float4 d = *(float4*)(&red[3][j4]);
        float4 r;
        r.x = s0 + a.x + c.x + d.x;
        r.y = s1 + a.y + c.y + d.y;
        r.z = s2 + a.z + c.z + d.z;
        r.w = s3 + a.w + c.w + d.w;
        *(float4*)(embp + ((size_t)b * 9 + seg) * 256 + j4) = r;
    }
}

// ---------------------------------------------------------------------------
// K5: view linear + scalar scores (embp holds 9 partial SUMS per image)
// ---------------------------------------------------------------------------
__global__ __launch_bounds__(256) void view_linear(const float* __restrict__ embp,
                                                   const float* __restrict__ Wv,
                                                   const float* __restrict__ att_s,
                                                   const float* __restrict__ att_d,
                                                   float* __restrict__ hv,
                                                   float* __restrict__ asv,
                                                   float* __restrict__ adv) {
    __shared__ float er[256];
    __shared__ float red[2][256];
    const int i = blockIdx.x;
    const int j = threadIdx.x;
    const int i64 = i & 63;
    float s = 0.f;
#pragma unroll
    for (int seg = 0; seg < 9; ++seg) s += embp[((size_t)i64 * 9 + seg) * 256 + j];
    er[j] = s * (1.f / 576.f);
    __syncthreads();
    float acc = 0.f;
    for (int c = 0; c < 256; ++c) acc += er[c] * Wv[c * 256 + j];
    hv[(size_t)i * 256 + j] = acc;
    red[0][j] = acc * att_s[j];
    red[1][j] = acc * att_d[j];
    __syncthreads();
    for (int off = 128; off > 0; off >>= 1) {
        if (j < off) { red[0][j] += red[0][j + off]; red[1][j] += red[1][j + off]; }
        __syncthreads();
    }
    if (j == 0) { asv[i] = red[0][0]; adv[i] = red[1][0]; }
}

// ---------------------------------------------------------------------------
// K6: view GAT gather for dst 0..63
// ---------------------------------------------------------------------------
__global__ __launch_bounds__(256) void view_gather(const float* __restrict__ hv,
                                                   const float* __restrict__ asv,
                                                   const float* __restrict__ adv,
                                                   const int* __restrict__ ev,
                                                   int Ev,
                                                   const float* __restrict__ bias,
                                                   float* __restrict__ feat) {
    __shared__ int cnt;
    __shared__ int s_src[32];
    const int d = blockIdx.x;
    const int t = threadIdx.x;
    if (t == 0) cnt = 0;
    __syncthreads();
    for (int e = t; e < Ev; e += 256) {
        if (ev[Ev + e] == d) {
            int pos = atomicAdd(&cnt, 1);
            s_src[pos] = ev[e];
        }
    }
    __syncthreads();
    const int ns = cnt;
    const float adval = adv[d];
    float m = -1e30f;
    float ev_[16];
#pragma unroll 1
    for (int k = 0; k < ns; ++k) {
        float e = asv[s_src[k]] + adval;
        e = e >= 0.f ? e : 0.2f * e;
        ev_[k] = e;
        m = fmaxf(m, e);
    }
    float eself = asv[d] + adval;
    eself = eself >= 0.f ? eself : 0.2f * eself;
    m = fmaxf(m, eself);
    float ssum = 0.f;
#pragma unroll 1
    for (int k = 0; k < ns; ++k) { ev_[k] = __expf(ev_[k] - m); ssum += ev_[k]; }
    float wself = __expf(eself - m);
    ssum += wself;
    const float inv = 1.f / (ssum + 1e-16f);
    float out = 0.f;
#pragma unroll 1
    for (int k = 0; k < ns; ++k) out += ev_[k] * hv[(size_t)s_src[k] * 256 + t];
    out += wself * hv[(size_t)d * 256 + t];
    feat[d * 256 + t] = out * inv + bias[t];
}

// ---------------------------------------------------------------------------
// K7: out = 0.5*xs(bf16) + 0.5*feat[b]
// ---------------------------------------------------------------------------
__global__ __launch_bounds__(256) void combine(const unsigned short* __restrict__ xsb,
                                               const float* __restrict__ feat,
                                               float* __restrict__ out, int ntot4) {
    int i = blockIdx.x * blockDim.x + threadIdx.x;
    if (i >= ntot4) return;
    size_t f = (size_t)i * 4;
    int b = (int)(f / (PGRID * 256));
    int j = (int)(f & 255);
    uint2 v = *(const uint2*)(xsb + f);
    float4 fb = *(const float4*)(feat + b * 256 + j);
    float4 o;
    o.x = 0.5f * (bf2f((unsigned short)(v.x & 0xffff)) + fb.x);
    o.y = 0.5f * (bf2f((unsigned short)(v.x >> 16))   + fb.y);
    o.z = 0.5f * (bf2f((unsigned short)(v.y & 0xffff)) + fb.z);
    o.w = 0.5f * (bf2f((unsigned short)(v.y >> 16))   + fb.w);
    *(float4*)(out + f) = o;
}

// ---------------------------------------------------------------------------
extern "C" void kernel_launch(void* const* d_in, const int* in_sizes, int n_in,
                              void* d_out, int out_size, void* d_ws, size_t ws_size,
                              hipStream_t stream) {
    const float* x        = (const float*)d_in[0];
    const int*   e_space  = (const int*)d_in[3];
    const int*   e_view   = (const int*)d_in[4];
    const float* W_space  = (const float*)d_in[5];
    const float* att_ss   = (const float*)d_in[6];
    const float* att_ds   = (const float*)d_in[7];
    const float* bias_s   = (const float*)d_in[8];
    const float* W_view   = (const float*)d_in[9];
    const float* att_sv   = (const float*)d_in[10];
    const float* att_dv   = (const float*)d_in[11];
    const float* bias_v   = (const float*)d_in[12];
    float* out = (float*)d_out;

    const int Ev = in_sizes[4] / 2;

    // workspace layout (bytes)
    char* ws = (char*)d_ws;
    unsigned short* hbf = (unsigned short*)ws;                       // 18.9 MB
    unsigned short* Wt  = (unsigned short*)(ws + 18874368);          // 128 KB
    unsigned short* xsb = (unsigned short*)(ws + 18874368 + 131072); // 18.9 MB
    float* as_  = (float*)(ws + 2 * 18874368 + 131072);
    float* ad_  = as_ + NNODE * 2;
    float* embp = ad_ + NNODE * 2;                                   // 64*9*256
    float* hv   = embp + 64 * 9 * 256;
    float* asv  = hv  + 128 * 256;
    float* adv  = asv + 128;
    float* feat = adv + 128;

    prep_w<<<dim3(4, 4), 256, 0, stream>>>(W_space, Wt);
    gemm_fused<<<576, 256, 0, stream>>>(x, Wt, att_ss, att_ds, hbf, as_, ad_);
    space_gather<<<NNODE / 4, 256, 0, stream>>>(hbf, as_, ad_, e_space, bias_s, xsb);
    pool_partial<<<dim3(NB0, 9), 256, 0, stream>>>(xsb, embp);
    view_linear<<<128, 256, 0, stream>>>(embp, W_view, att_sv, att_dv, hv, asv, adv);
    view_gather<<<NB0, 256, 0, stream>>>(hv, asv, adv, e_view, Ev, bias_v, feat);

    const int ntot4 = NB0 * PGRID * 256 / 4;
    combine<<<(ntot4 + 255) / 256, 256, 0, stream>>>(xsb, feat, out, ntot4);
}